// Round 4
// baseline (523.600 us; speedup 1.0000x reference)
//
#include <hip/hip_runtime.h>
#include <math.h>

#define Bsz 8
#define Ssz 2048
#define Dsz 1024
#define Nsz 1024
#define CHUNKS 64
#define CLEN 32
#define Msz (Bsz * Ssz)   // 16384
#define Ksz 1024

typedef unsigned short u16;
typedef __attribute__((ext_vector_type(8))) short short8;
typedef __attribute__((ext_vector_type(4))) float floatx4;

__device__ __forceinline__ float b2f(u16 u) {
    unsigned v = ((unsigned)u) << 16; float f; __builtin_memcpy(&f, &v, 4); return f;
}
__device__ __forceinline__ u16 f2b(float f) {
    unsigned u; __builtin_memcpy(&u, &f, 4);
    unsigned r = u + 0x7fffu + ((u >> 16) & 1u);
    return (u16)(r >> 16);
}

// ---------------- merged fp32 -> bf16 converts (one dispatch, 8 jobs) ----------------
struct CvtJobs {
    const float* src[8];
    u16* dst[8];
    int n4[8];
    float scale[8];
    int blk_start[9];
};

__global__ __launch_bounds__(256)
void cvt_multi(CvtJobs J) {
    int b = blockIdx.x;
    int j = 0;
    #pragma unroll
    for (int t = 0; t < 7; ++t) if (b >= J.blk_start[t + 1]) j = t + 1;
    int i = (b - J.blk_start[j]) * 256 + threadIdx.x;
    if (i < J.n4[j]) {
        float4 v = ((const float4*)J.src[j])[i];
        float s = J.scale[j];
        ushort4 o;
        o.x = f2b(v.x * s); o.y = f2b(v.y * s);
        o.z = f2b(v.z * s); o.w = f2b(v.w * s);
        ((ushort4*)J.dst[j])[i] = o;
    }
}

// ---------------- lambda / gamma setup ----------------
__global__ void lam_setup(const float* __restrict__ nu_log, const float* __restrict__ theta_log,
                          float* lam_re, float* lam_im, float* gam,
                          float* lamL_re, float* lamL_im) {
    int n = blockIdx.x * 256 + threadIdx.x;
    if (n >= Nsz) return;
    float mag = expf(-expf(nu_log[n]));
    float ph  = expf(theta_log[n]);
    float lr = mag * cosf(ph), li = mag * sinf(ph);
    lam_re[n] = lr; lam_im[n] = li;
    gam[n] = sqrtf(fmaxf(1.0f - mag * mag, 0.0f));
    float ar = lr, ai = li;
    #pragma unroll
    for (int i = 0; i < 5; ++i) { float nr = ar*ar - ai*ai; float ni = 2.0f*ar*ai; ar = nr; ai = ni; }  // lam^32
    lamL_re[n] = ar; lamL_im[n] = ai;
}

// ---------------- bf16 GEMM, BK=32, double-buffered LDS, 1 barrier/iter ----------------
// A: [M,K] bf16 row-major, W: [N,K] bf16 row-major. M=16384, N=K=1024 hardcoded.
// LDS swizzle (R2-verified, 0 conflicts): LDS[row][chunk c] = global[row][c ^ ((row>>1)&3)]
#define BM 128
#define BN 128
#define BK 32
#define KITER 32   // K / BK

struct GemmJob {
    const u16* A0; const u16* W0;
    const u16* A1; const u16* W1;
    const u16* A2; const u16* W2;
    int P;
    float* outF;          // if non-null: fp32 out
    u16*   outB;          // else bf16 out
    const float* colscale; // optional per-col scale
};
struct GemmBatch { GemmJob j[3]; };

__global__ __launch_bounds__(256, 3)
void gemm_bt(GemmBatch batch) {
    const GemmJob job = batch.j[blockIdx.z];
    __shared__ u16 As[2][BM * BK];   // 2 x 8 KB
    __shared__ u16 Ws[2][BN * BK];   // 2 x 8 KB
    const int tid  = threadIdx.x;
    const int wave = tid >> 6, lane = tid & 63;
    const int bm = blockIdx.x, bn = blockIdx.y;
    const int wm = (wave >> 1) * 64, wn = (wave & 1) * 64;

    floatx4 acc[4][4];
    #pragma unroll
    for (int i = 0; i < 4; ++i)
        #pragma unroll
        for (int j = 0; j < 4; ++j) acc[i][j] = (floatx4){0.f, 0.f, 0.f, 0.f};

    const u16* Aps[3] = { job.A0, job.A1, job.A2 };
    const u16* Wps[3] = { job.W0, job.W1, job.W2 };
    const int TOT = job.P * KITER;

    // staging: lane l -> row l>>2, chunk l&3, swizzled global chunk (l&3)^((l>>3)&3)
    const int srow = wave * 32 + (lane >> 2);
    const int scol = ((lane & 3) ^ ((lane >> 3) & 3)) * 8;
    const size_t sAoff = (size_t)(bm * BM + srow) * Ksz + scol;
    const size_t sWoff = (size_t)(bn * BN + srow) * Ksz + scol;
    // fragments
    const int frow = lane & 15;
    const int fk   = (((lane >> 4) ^ ((frow >> 1) & 3))) * 8;  // swizzled LDS k-offset (elements)

    // prologue: stage iter 0 into buf 0
    {
        const u16* gA = Aps[0] + sAoff;
        const u16* gW = Wps[0] + sWoff;
        #pragma unroll
        for (int jj = 0; jj < 2; ++jj) {
            u16* lA = &As[0][(wave * 32 + jj * 16) * BK];
            u16* lW = &Ws[0][(wave * 32 + jj * 16) * BK];
            __builtin_amdgcn_global_load_lds((const __attribute__((address_space(1))) void*)(gA + (size_t)(jj * 16) * Ksz),
                                             (__attribute__((address_space(3))) void*)lA, 16, 0, 0);
            __builtin_amdgcn_global_load_lds((const __attribute__((address_space(1))) void*)(gW + (size_t)(jj * 16) * Ksz),
                                             (__attribute__((address_space(3))) void*)lW, 16, 0, 0);
        }
    }

    for (int i = 0; i < TOT; ++i) {
        const int cur = i & 1;
        __syncthreads();   // loads for iter i complete; buf[cur^1] free to overwrite
        if (i + 1 < TOT) {
            const int ni = i + 1;
            const int p = ni >> 5;           // ni / KITER
            const int koff = (ni & 31) * BK; // (ni % KITER) * BK
            const u16* gA = Aps[p] + sAoff + koff;
            const u16* gW = Wps[p] + sWoff + koff;
            const int nb = cur ^ 1;
            #pragma unroll
            for (int jj = 0; jj < 2; ++jj) {
                u16* lA = &As[nb][(wave * 32 + jj * 16) * BK];
                u16* lW = &Ws[nb][(wave * 32 + jj * 16) * BK];
                __builtin_amdgcn_global_load_lds((const __attribute__((address_space(1))) void*)(gA + (size_t)(jj * 16) * Ksz),
                                                 (__attribute__((address_space(3))) void*)lA, 16, 0, 0);
                __builtin_amdgcn_global_load_lds((const __attribute__((address_space(1))) void*)(gW + (size_t)(jj * 16) * Ksz),
                                                 (__attribute__((address_space(3))) void*)lW, 16, 0, 0);
            }
        }
        short8 af[4], wf[4];
        #pragma unroll
        for (int t = 0; t < 4; ++t)
            af[t] = *(const short8*)(&As[cur][(wm + t * 16 + frow) * BK + fk]);
        #pragma unroll
        for (int t = 0; t < 4; ++t)
            wf[t] = *(const short8*)(&Ws[cur][(wn + t * 16 + frow) * BK + fk]);
        #pragma unroll
        for (int mi = 0; mi < 4; ++mi)
            #pragma unroll
            for (int ni2 = 0; ni2 < 4; ++ni2)
                acc[mi][ni2] = __builtin_amdgcn_mfma_f32_16x16x32_bf16(af[mi], wf[ni2], acc[mi][ni2], 0, 0, 0);
    }

    // epilogue: C/D layout col=lane&15, row=(lane>>4)*4+r
    const int rgrp = lane >> 4;
    const int ccol = lane & 15;
    #pragma unroll
    for (int mi = 0; mi < 4; ++mi) {
        #pragma unroll
        for (int r = 0; r < 4; ++r) {
            int row = bm * BM + wm + mi * 16 + rgrp * 4 + r;
            #pragma unroll
            for (int ni = 0; ni < 4; ++ni) {
                int col = bn * BN + wn + ni * 16 + ccol;
                float v = acc[mi][ni][r];
                if (job.colscale) v *= job.colscale[col];
                size_t idx = (size_t)row * Nsz + col;
                if (job.outF) job.outF[idx] = v;
                else          job.outB[idx] = f2b(v);
            }
        }
    }
}

// ---------------- chunked scan (vectorized over 4 consecutive n) ----------------
__global__ void scan_phase1(const u16* __restrict__ u_re, const u16* __restrict__ u_im,
                            const float* __restrict__ lam_re, const float* __restrict__ lam_im,
                            float* __restrict__ carry_re, float* __restrict__ carry_im) {
    int n = threadIdx.x * 4;               // 256 threads cover N=1024
    int c = blockIdx.x, b = blockIdx.y;
    float4 lr = *(const float4*)(lam_re + n);
    float4 li = *(const float4*)(lam_im + n);
    size_t base = ((size_t)b * Ssz + (size_t)c * CLEN) * Nsz + n;
    float hr[4] = {0.f, 0.f, 0.f, 0.f}, hi[4] = {0.f, 0.f, 0.f, 0.f};
    const float* lrp = (const float*)&lr; const float* lip = (const float*)&li;
    #pragma unroll
    for (int t = 0; t < CLEN; ++t) {
        ushort4 urv = *(const ushort4*)(u_re + base + (size_t)t * Nsz);
        ushort4 uiv = *(const ushort4*)(u_im + base + (size_t)t * Nsz);
        float ur[4] = { b2f(urv.x), b2f(urv.y), b2f(urv.z), b2f(urv.w) };
        float ui[4] = { b2f(uiv.x), b2f(uiv.y), b2f(uiv.z), b2f(uiv.w) };
        #pragma unroll
        for (int q = 0; q < 4; ++q) {
            float nr = fmaf(lrp[q], hr[q], fmaf(-lip[q], hi[q], ur[q]));
            float ni = fmaf(lrp[q], hi[q], fmaf( lip[q], hr[q], ui[q]));
            hr[q] = nr; hi[q] = ni;
        }
    }
    size_t ci = ((size_t)b * CHUNKS + c) * Nsz + n;
    *(float4*)(carry_re + ci) = (float4){hr[0], hr[1], hr[2], hr[3]};
    *(float4*)(carry_im + ci) = (float4){hi[0], hi[1], hi[2], hi[3]};
}

__global__ void scan_phase2(const float* __restrict__ carry_re, const float* __restrict__ carry_im,
                            const float* __restrict__ lamL_re, const float* __restrict__ lamL_im,
                            const float* __restrict__ hid_re, const float* __restrict__ hid_im,
                            float* __restrict__ entry_re, float* __restrict__ entry_im,
                            float* __restrict__ out_base) {
    int n = blockIdx.x * 256 + threadIdx.x;
    int b = blockIdx.y;
    float Lr = lamL_re[n], Li = lamL_im[n];
    float Hr = hid_re[b * Nsz + n], Hi = hid_im[b * Nsz + n];
    for (int c = 0; c < CHUNKS; ++c) {
        size_t ci = ((size_t)b * CHUNKS + c) * Nsz + n;
        entry_re[ci] = Hr; entry_im[ci] = Hi;
        float cr = carry_re[ci], cim = carry_im[ci];
        float nr = fmaf(Lr, Hr, fmaf(-Li, Hi, cr));
        float ni = fmaf(Lr, Hi, fmaf( Li, Hr, cim));
        Hr = nr; Hi = ni;
    }
    out_base[(size_t)16777216 + (size_t)b * Nsz + n] = Hr;           // hf_re
    out_base[(size_t)16777216 + 8192 + (size_t)b * Nsz + n] = Hi;    // hf_im
}

__global__ void scan_phase3(const u16* __restrict__ u_re, const u16* __restrict__ u_im,
                            const float* __restrict__ lam_re, const float* __restrict__ lam_im,
                            const float* __restrict__ entry_re, const float* __restrict__ entry_im,
                            u16* __restrict__ hs_re, u16* __restrict__ hs_im) {
    int n = threadIdx.x * 4;
    int c = blockIdx.x, b = blockIdx.y;
    float4 lr = *(const float4*)(lam_re + n);
    float4 li = *(const float4*)(lam_im + n);
    const float* lrp = (const float*)&lr; const float* lip = (const float*)&li;
    size_t ci = ((size_t)b * CHUNKS + c) * Nsz + n;
    float4 er = *(const float4*)(entry_re + ci);
    float4 ei = *(const float4*)(entry_im + ci);
    float hr[4] = {er.x, er.y, er.z, er.w}, hi[4] = {ei.x, ei.y, ei.z, ei.w};
    size_t base = ((size_t)b * Ssz + (size_t)c * CLEN) * Nsz + n;
    #pragma unroll
    for (int t = 0; t < CLEN; ++t) {
        ushort4 urv = *(const ushort4*)(u_re + base + (size_t)t * Nsz);
        ushort4 uiv = *(const ushort4*)(u_im + base + (size_t)t * Nsz);
        float ur[4] = { b2f(urv.x), b2f(urv.y), b2f(urv.z), b2f(urv.w) };
        float ui[4] = { b2f(uiv.x), b2f(uiv.y), b2f(uiv.z), b2f(uiv.w) };
        ushort4 orv, oiv;
        u16* orp = (u16*)&orv; u16* oip = (u16*)&oiv;
        #pragma unroll
        for (int q = 0; q < 4; ++q) {
            float nr = fmaf(lrp[q], hr[q], fmaf(-lip[q], hi[q], ur[q]));
            float ni = fmaf(lrp[q], hi[q], fmaf( lip[q], hr[q], ui[q]));
            hr[q] = nr; hi[q] = ni;
            orp[q] = f2b(nr); oip[q] = f2b(ni);
        }
        *(ushort4*)(hs_re + base + (size_t)t * Nsz) = orv;
        *(ushort4*)(hs_im + base + (size_t)t * Nsz) = oiv;
    }
}

// ---------------- fused LN -> gelu(LN(gate)) -> mult -> LN -> gelu ----------------
__device__ __forceinline__ float waveReduce(float v) {
    #pragma unroll
    for (int off = 32; off > 0; off >>= 1) v += __shfl_down(v, off, 64);
    return v;
}
__device__ __forceinline__ float gelu_exact(float x) {
    return 0.5f * x * (1.0f + erff(x * 0.70710678118654752f));
}

__global__ __launch_bounds__(256)
void fuse_ln(const u16* __restrict__ y_raw, const u16* __restrict__ gate_pre, u16* __restrict__ y3) {
    int row = blockIdx.x;
    int tid = threadIdx.x;
    int wave = tid >> 6, lane = tid & 63;
    size_t base = (size_t)row * Nsz + tid * 4;
    ushort4 yv = *(const ushort4*)(y_raw + base);
    ushort4 gv = *(const ushort4*)(gate_pre + base);
    float y[4] = { b2f(yv.x), b2f(yv.y), b2f(yv.z), b2f(yv.w) };
    float g[4] = { b2f(gv.x), b2f(gv.y), b2f(gv.z), b2f(gv.w) };

    float sy = 0.f, sy2 = 0.f, sg = 0.f, sg2 = 0.f;
    #pragma unroll
    for (int i = 0; i < 4; ++i) {
        sy += y[i]; sy2 += y[i] * y[i];
        sg += g[i]; sg2 += g[i] * g[i];
    }
    __shared__ float sh[16];
    sy = waveReduce(sy); sy2 = waveReduce(sy2);
    sg = waveReduce(sg); sg2 = waveReduce(sg2);
    if (lane == 0) { sh[wave] = sy; sh[wave + 4] = sy2; sh[wave + 8] = sg; sh[wave + 12] = sg2; }
    __syncthreads();
    sy  = sh[0] + sh[1] + sh[2] + sh[3];
    sy2 = sh[4] + sh[5] + sh[6] + sh[7];
    sg  = sh[8] + sh[9] + sh[10] + sh[11];
    sg2 = sh[12] + sh[13] + sh[14] + sh[15];
    const float inv = 1.0f / (float)Nsz;
    float muy = sy * inv, vary = sy2 * inv - muy * muy, ry = rsqrtf(vary + 1e-5f);
    float mug = sg * inv, varg = sg2 * inv - mug * mug, rg = rsqrtf(varg + 1e-5f);

    float y2[4]; float s2 = 0.f, s22 = 0.f;
    #pragma unroll
    for (int i = 0; i < 4; ++i) {
        float ly = (y[i] - muy) * ry;
        float lg = (g[i] - mug) * rg;
        float t = ly * gelu_exact(lg);
        y2[i] = t; s2 += t; s22 += t * t;
    }
    s2 = waveReduce(s2); s22 = waveReduce(s22);
    __syncthreads();
    if (lane == 0) { sh[wave] = s2; sh[wave + 4] = s22; }
    __syncthreads();
    s2  = sh[0] + sh[1] + sh[2] + sh[3];
    s22 = sh[4] + sh[5] + sh[6] + sh[7];
    float mu2 = s2 * inv, var2 = s22 * inv - mu2 * mu2, r2 = rsqrtf(var2 + 1e-5f);
    ushort4 ov;
    ov.x = f2b(gelu_exact((y2[0] - mu2) * r2));
    ov.y = f2b(gelu_exact((y2[1] - mu2) * r2));
    ov.z = f2b(gelu_exact((y2[2] - mu2) * r2));
    ov.w = f2b(gelu_exact((y2[3] - mu2) * r2));
    *(ushort4*)(y3 + base) = ov;
}

// ---------------- host launch ----------------
extern "C" void kernel_launch(void* const* d_in, const int* in_sizes, int n_in,
                              void* d_out, int out_size, void* d_ws, size_t ws_size,
                              hipStream_t stream) {
    const float* x         = (const float*)d_in[0];
    const float* hid_re    = (const float*)d_in[1];
    const float* hid_im    = (const float*)d_in[2];
    const float* nu_log    = (const float*)d_in[3];
    const float* theta_log = (const float*)d_in[4];
    const float* B_re      = (const float*)d_in[5];
    const float* B_im      = (const float*)d_in[6];
    const float* C_re      = (const float*)d_in[7];
    const float* C_im      = (const float*)d_in[8];
    const float* D_skip    = (const float*)d_in[9];
    const float* W_gate    = (const float*)d_in[10];
    const float* W_con     = (const float*)d_in[11];
    float* out = (float*)d_out;

    char* ws = (char*)d_ws;
    const size_t MB = 1ull << 20;
    u16* wBre  = (u16*)(ws + 0 * MB);
    u16* wBim  = (u16*)(ws + 2 * MB);
    u16* wCre  = (u16*)(ws + 4 * MB);
    u16* wCimN = (u16*)(ws + 6 * MB);
    u16* wDsk  = (u16*)(ws + 8 * MB);
    u16* wWg   = (u16*)(ws + 10 * MB);
    u16* wWc   = (u16*)(ws + 12 * MB);
    float* lam_re = (float*)(ws + 14 * MB);
    float* lam_im = lam_re + 1024;
    float* gam    = lam_re + 2048;
    float* lamLre = lam_re + 3072;
    float* lamLim = lam_re + 4096;
    u16* xb    = (u16*)(ws + 16 * MB);
    u16* u_re  = (u16*)(ws + 48 * MB);
    u16* u_im  = (u16*)(ws + 80 * MB);
    u16* gate  = (u16*)(ws + 112 * MB);
    u16* hs_re = (u16*)(ws + 144 * MB);
    u16* hs_im = (u16*)(ws + 176 * MB);
    float* carry_re = (float*)(ws + 208 * MB);
    float* carry_im = (float*)(ws + 210 * MB);
    float* entry_re = (float*)(ws + 212 * MB);
    float* entry_im = (float*)(ws + 214 * MB);
    u16* y_raw = u_re;  // alias: u dead after scan_phase3
    u16* y3    = u_im;  // alias

    // merged converts (1 dispatch)
    CvtJobs J = {};
    const int WQ = (Nsz * Dsz) / 4;        // 262144 quads per weight
    const int WB = WQ / 256;               // 1024 blocks per weight
    J.src[0] = x;      J.dst[0] = xb;    J.n4[0] = (Msz * Dsz) / 4; J.scale[0] = 1.0f;
    J.src[1] = B_re;   J.dst[1] = wBre;  J.n4[1] = WQ; J.scale[1] = 1.0f;
    J.src[2] = B_im;   J.dst[2] = wBim;  J.n4[2] = WQ; J.scale[2] = 1.0f;
    J.src[3] = C_re;   J.dst[3] = wCre;  J.n4[3] = WQ; J.scale[3] = 1.0f;
    J.src[4] = C_im;   J.dst[4] = wCimN; J.n4[4] = WQ; J.scale[4] = -1.0f;
    J.src[5] = D_skip; J.dst[5] = wDsk;  J.n4[5] = WQ; J.scale[5] = 1.0f;
    J.src[6] = W_gate; J.dst[6] = wWg;   J.n4[6] = WQ; J.scale[6] = 1.0f;
    J.src[7] = W_con;  J.dst[7] = wWc;   J.n4[7] = WQ; J.scale[7] = 1.0f;
    J.blk_start[0] = 0;
    J.blk_start[1] = 16384;
    for (int t = 2; t <= 8; ++t) J.blk_start[t] = J.blk_start[t - 1] + WB;
    cvt_multi<<<J.blk_start[8], 256, 0, stream>>>(J);
    lam_setup<<<4, 256, 0, stream>>>(nu_log, theta_log, lam_re, lam_im, gam, lamLre, lamLim);

    // GEMM batch 1: u_re, u_im (gamma-scaled), gate_pre
    GemmBatch b1 = {};
    b1.j[0] = { xb, wBre, nullptr, nullptr, nullptr, nullptr, 1, nullptr, u_re, gam };
    b1.j[1] = { xb, wBim, nullptr, nullptr, nullptr, nullptr, 1, nullptr, u_im, gam };
    b1.j[2] = { xb, wWg,  nullptr, nullptr, nullptr, nullptr, 1, nullptr, gate, nullptr };
    gemm_bt<<<dim3(Msz / BM, Nsz / BN, 3), 256, 0, stream>>>(b1);

    // scan
    scan_phase1<<<dim3(CHUNKS, Bsz), 256, 0, stream>>>(u_re, u_im, lam_re, lam_im, carry_re, carry_im);
    scan_phase2<<<dim3(Nsz / 256, Bsz), 256, 0, stream>>>(carry_re, carry_im, lamLre, lamLim,
                                                          hid_re, hid_im, entry_re, entry_im, out);
    scan_phase3<<<dim3(CHUNKS, Bsz), 256, 0, stream>>>(u_re, u_im, lam_re, lam_im,
                                                       entry_re, entry_im, hs_re, hs_im);

    // GEMM batch 2: y_raw = hs_re*C_re^T + hs_im*(-C_im)^T + x*D_skip^T
    GemmBatch b2 = {};
    b2.j[0] = { hs_re, wCre, hs_im, wCimN, xb, wDsk, 3, nullptr, y_raw, nullptr };
    gemm_bt<<<dim3(Msz / BM, Nsz / BN, 1), 256, 0, stream>>>(b2);

    // fused LN / gate / gelu
    fuse_ln<<<Msz, 256, 0, stream>>>(y_raw, gate, y3);

    // GEMM 3: out = y3 * W_con^T  (fp32 out)
    GemmBatch b3 = {};
    b3.j[0] = { y3, wWc, nullptr, nullptr, nullptr, nullptr, 1, out, nullptr, nullptr };
    gemm_bt<<<dim3(Msz / BM, Dsz / BN, 1), 256, 0, stream>>>(b3);

    (void)in_sizes; (void)n_in; (void)out_size; (void)ws_size;
}

// Round 5
// 482.307 us; speedup vs baseline: 1.0856x; 1.0856x over previous
//
#include <hip/hip_runtime.h>
#include <math.h>

#define Bsz 8
#define Ssz 2048
#define Dsz 1024
#define Nsz 1024
#define CHUNKS 64
#define CLEN 32
#define Msz (Bsz * Ssz)   // 16384
#define Ksz 1024

typedef unsigned short u16;
typedef __attribute__((ext_vector_type(8))) short short8;
typedef __attribute__((ext_vector_type(4))) float floatx4;

__device__ __forceinline__ float b2f(u16 u) {
    unsigned v = ((unsigned)u) << 16; float f; __builtin_memcpy(&f, &v, 4); return f;
}
__device__ __forceinline__ u16 f2b(float f) {
    unsigned u; __builtin_memcpy(&u, &f, 4);
    unsigned r = u + 0x7fffu + ((u >> 16) & 1u);
    return (u16)(r >> 16);
}

// ---------------- merged fp32 -> bf16 converts (one dispatch, 8 jobs) ----------------
struct CvtJobs {
    const float* src[8];
    u16* dst[8];
    int n4[8];
    float scale[8];
    int blk_start[9];
};

__global__ __launch_bounds__(256)
void cvt_multi(CvtJobs J) {
    int b = blockIdx.x;
    int j = 0;
    #pragma unroll
    for (int t = 0; t < 7; ++t) if (b >= J.blk_start[t + 1]) j = t + 1;
    int i = (b - J.blk_start[j]) * 256 + threadIdx.x;
    if (i < J.n4[j]) {
        float4 v = ((const float4*)J.src[j])[i];
        float s = J.scale[j];
        ushort4 o;
        o.x = f2b(v.x * s); o.y = f2b(v.y * s);
        o.z = f2b(v.z * s); o.w = f2b(v.w * s);
        ((ushort4*)J.dst[j])[i] = o;
    }
}

// ---------------- lambda / gamma setup ----------------
__global__ void lam_setup(const float* __restrict__ nu_log, const float* __restrict__ theta_log,
                          float* lam_re, float* lam_im, float* gam,
                          float* lamL_re, float* lamL_im) {
    int n = blockIdx.x * 256 + threadIdx.x;
    if (n >= Nsz) return;
    float mag = expf(-expf(nu_log[n]));
    float ph  = expf(theta_log[n]);
    float lr = mag * cosf(ph), li = mag * sinf(ph);
    lam_re[n] = lr; lam_im[n] = li;
    gam[n] = sqrtf(fmaxf(1.0f - mag * mag, 0.0f));
    float ar = lr, ai = li;
    #pragma unroll
    for (int i = 0; i < 5; ++i) { float nr = ar*ar - ai*ai; float ni = 2.0f*ar*ai; ar = nr; ai = ni; }  // lam^32
    lamL_re[n] = ar; lamL_im[n] = ai;
}

// ---------------- bf16 GEMM: 256x128 block, 128x64 per wave, BK=64, single-buffer ----------------
// A: [M,K] bf16 row-major, W: [N,K] bf16 row-major. K=1024 hardcoded.
// LDS swizzle (R3-verified, 0 conflicts): LDS[row][g ^ (row&7)] = global[row][g]  (16B chunks)
#define BM 256
#define BN 128
#define BK 64
#define KITER 16   // K / BK

struct GemmJob {
    const u16* A0; const u16* W0;
    const u16* A1; const u16* W1;
    const u16* A2; const u16* W2;
    int P;
    float* outF;          // if non-null: fp32 out
    u16*   outB;          // else bf16 out
    const float* colscale; // optional per-col scale
};
struct GemmBatch { GemmJob j[3]; };

__global__ __launch_bounds__(256, 2)
void gemm_bt(GemmBatch batch) {
    const GemmJob job = batch.j[blockIdx.z];
    __shared__ u16 As[BM * BK];   // 32 KB
    __shared__ u16 Ws[BN * BK];   // 16 KB
    const int tid  = threadIdx.x;
    const int wave = tid >> 6, lane = tid & 63;
    const int bm = blockIdx.x, bn = blockIdx.y;
    const int wm = (wave >> 1) * 128;   // 0 or 128
    const int wn = (wave & 1) * 64;     // 0 or 64

    floatx4 acc[8][4];
    #pragma unroll
    for (int i = 0; i < 8; ++i)
        #pragma unroll
        for (int j = 0; j < 4; ++j) acc[i][j] = (floatx4){0.f, 0.f, 0.f, 0.f};

    const u16* Aps[3] = { job.A0, job.A1, job.A2 };
    const u16* Wps[3] = { job.W0, job.W1, job.W2 };
    const int TOT = job.P * KITER;

    // staging: each global_load_lds moves 8 rows x 128B; lane l -> row l>>3, chunk (l&7)^(l>>3)
    const int srow8 = lane >> 3;                       // 0..7
    const int scol  = ((lane & 7) ^ srow8) * 8;        // swizzled global col (elements)
    const size_t sAbase = (size_t)(bm * BM + wave * 64 + srow8) * Ksz + scol;  // 8 jj-groups of 8 rows
    const size_t sWbase = (size_t)(bn * BN + wave * 32 + srow8) * Ksz + scol;  // 4 jj-groups of 8 rows
    // fragments
    const int frow = lane & 15;
    const int fq   = lane >> 4;         // k-chunk within 32-half
    const int fsw  = frow & 7;          // swizzle key

    for (int i = 0; i < TOT; ++i) {
        const int p    = i >> 4;
        const int koff = (i & 15) * BK;
        const u16* Ap = Aps[p];
        const u16* Wp = Wps[p];
        __syncthreads();
        #pragma unroll
        for (int jj = 0; jj < 8; ++jj) {
            const u16* g = Ap + sAbase + (size_t)(jj * 8) * Ksz + koff;
            u16* l = &As[(wave * 64 + jj * 8) * BK];
            __builtin_amdgcn_global_load_lds((const __attribute__((address_space(1))) void*)g,
                                             (__attribute__((address_space(3))) void*)l, 16, 0, 0);
        }
        #pragma unroll
        for (int jj = 0; jj < 4; ++jj) {
            const u16* g = Wp + sWbase + (size_t)(jj * 8) * Ksz + koff;
            u16* l = &Ws[(wave * 32 + jj * 8) * BK];
            __builtin_amdgcn_global_load_lds((const __attribute__((address_space(1))) void*)g,
                                             (__attribute__((address_space(3))) void*)l, 16, 0, 0);
        }
        __syncthreads();
        #pragma unroll
        for (int h = 0; h < 2; ++h) {
            const int ca = ((h << 2) | fq) ^ fsw;     // swizzled LDS chunk
            short8 af[8], wf[4];
            #pragma unroll
            for (int t = 0; t < 8; ++t)
                af[t] = *(const short8*)(&As[(wm + t * 16 + frow) * BK + ca * 8]);
            #pragma unroll
            for (int t = 0; t < 4; ++t)
                wf[t] = *(const short8*)(&Ws[(wn + t * 16 + frow) * BK + ca * 8]);
            #pragma unroll
            for (int mi = 0; mi < 8; ++mi)
                #pragma unroll
                for (int ni = 0; ni < 4; ++ni)
                    acc[mi][ni] = __builtin_amdgcn_mfma_f32_16x16x32_bf16(af[mi], wf[ni], acc[mi][ni], 0, 0, 0);
        }
    }

    // epilogue: C/D layout col=lane&15, row=(lane>>4)*4+r
    const int rgrp = lane >> 4;
    const int ccol = lane & 15;
    #pragma unroll
    for (int mi = 0; mi < 8; ++mi) {
        #pragma unroll
        for (int r = 0; r < 4; ++r) {
            int row = bm * BM + wm + mi * 16 + rgrp * 4 + r;
            #pragma unroll
            for (int ni = 0; ni < 4; ++ni) {
                int col = bn * BN + wn + ni * 16 + ccol;
                float v = acc[mi][ni][r];
                if (job.colscale) v *= job.colscale[col];
                size_t idx = (size_t)row * Nsz + col;
                if (job.outF) job.outF[idx] = v;
                else          job.outB[idx] = f2b(v);
            }
        }
    }
}

// ---------------- chunked scan (vectorized over 4 consecutive n) ----------------
__global__ void scan_phase1(const u16* __restrict__ u_re, const u16* __restrict__ u_im,
                            const float* __restrict__ lam_re, const float* __restrict__ lam_im,
                            float* __restrict__ carry_re, float* __restrict__ carry_im) {
    int n = threadIdx.x * 4;               // 256 threads cover N=1024
    int c = blockIdx.x, b = blockIdx.y;
    float4 lr = *(const float4*)(lam_re + n);
    float4 li = *(const float4*)(lam_im + n);
    size_t base = ((size_t)b * Ssz + (size_t)c * CLEN) * Nsz + n;
    float hr[4] = {0.f, 0.f, 0.f, 0.f}, hi[4] = {0.f, 0.f, 0.f, 0.f};
    const float* lrp = (const float*)&lr; const float* lip = (const float*)&li;
    #pragma unroll
    for (int t = 0; t < CLEN; ++t) {
        ushort4 urv = *(const ushort4*)(u_re + base + (size_t)t * Nsz);
        ushort4 uiv = *(const ushort4*)(u_im + base + (size_t)t * Nsz);
        float ur[4] = { b2f(urv.x), b2f(urv.y), b2f(urv.z), b2f(urv.w) };
        float ui[4] = { b2f(uiv.x), b2f(uiv.y), b2f(uiv.z), b2f(uiv.w) };
        #pragma unroll
        for (int q = 0; q < 4; ++q) {
            float nr = fmaf(lrp[q], hr[q], fmaf(-lip[q], hi[q], ur[q]));
            float ni = fmaf(lrp[q], hi[q], fmaf( lip[q], hr[q], ui[q]));
            hr[q] = nr; hi[q] = ni;
        }
    }
    size_t ci = ((size_t)b * CHUNKS + c) * Nsz + n;
    *(float4*)(carry_re + ci) = (float4){hr[0], hr[1], hr[2], hr[3]};
    *(float4*)(carry_im + ci) = (float4){hi[0], hi[1], hi[2], hi[3]};
}

__global__ void scan_phase2(const float* __restrict__ carry_re, const float* __restrict__ carry_im,
                            const float* __restrict__ lamL_re, const float* __restrict__ lamL_im,
                            const float* __restrict__ hid_re, const float* __restrict__ hid_im,
                            float* __restrict__ entry_re, float* __restrict__ entry_im,
                            float* __restrict__ out_base) {
    int n = blockIdx.x * 256 + threadIdx.x;
    int b = blockIdx.y;
    float Lr = lamL_re[n], Li = lamL_im[n];
    float Hr = hid_re[b * Nsz + n], Hi = hid_im[b * Nsz + n];
    for (int c = 0; c < CHUNKS; ++c) {
        size_t ci = ((size_t)b * CHUNKS + c) * Nsz + n;
        entry_re[ci] = Hr; entry_im[ci] = Hi;
        float cr = carry_re[ci], cim = carry_im[ci];
        float nr = fmaf(Lr, Hr, fmaf(-Li, Hi, cr));
        float ni = fmaf(Lr, Hi, fmaf( Li, Hr, cim));
        Hr = nr; Hi = ni;
    }
    out_base[(size_t)16777216 + (size_t)b * Nsz + n] = Hr;           // hf_re
    out_base[(size_t)16777216 + 8192 + (size_t)b * Nsz + n] = Hi;    // hf_im
}

__global__ void scan_phase3(const u16* __restrict__ u_re, const u16* __restrict__ u_im,
                            const float* __restrict__ lam_re, const float* __restrict__ lam_im,
                            const float* __restrict__ entry_re, const float* __restrict__ entry_im,
                            u16* __restrict__ hs_re, u16* __restrict__ hs_im) {
    int n = threadIdx.x * 4;
    int c = blockIdx.x, b = blockIdx.y;
    float4 lr = *(const float4*)(lam_re + n);
    float4 li = *(const float4*)(lam_im + n);
    const float* lrp = (const float*)&lr; const float* lip = (const float*)&li;
    size_t ci = ((size_t)b * CHUNKS + c) * Nsz + n;
    float4 er = *(const float4*)(entry_re + ci);
    float4 ei = *(const float4*)(entry_im + ci);
    float hr[4] = {er.x, er.y, er.z, er.w}, hi[4] = {ei.x, ei.y, ei.z, ei.w};
    size_t base = ((size_t)b * Ssz + (size_t)c * CLEN) * Nsz + n;
    #pragma unroll
    for (int t = 0; t < CLEN; ++t) {
        ushort4 urv = *(const ushort4*)(u_re + base + (size_t)t * Nsz);
        ushort4 uiv = *(const ushort4*)(u_im + base + (size_t)t * Nsz);
        float ur[4] = { b2f(urv.x), b2f(urv.y), b2f(urv.z), b2f(urv.w) };
        float ui[4] = { b2f(uiv.x), b2f(uiv.y), b2f(uiv.z), b2f(uiv.w) };
        ushort4 orv, oiv;
        u16* orp = (u16*)&orv; u16* oip = (u16*)&oiv;
        #pragma unroll
        for (int q = 0; q < 4; ++q) {
            float nr = fmaf(lrp[q], hr[q], fmaf(-lip[q], hi[q], ur[q]));
            float ni = fmaf(lrp[q], hi[q], fmaf( lip[q], hr[q], ui[q]));
            hr[q] = nr; hi[q] = ni;
            orp[q] = f2b(nr); oip[q] = f2b(ni);
        }
        *(ushort4*)(hs_re + base + (size_t)t * Nsz) = orv;
        *(ushort4*)(hs_im + base + (size_t)t * Nsz) = oiv;
    }
}

// ---------------- fused LN -> gelu(LN(gate)) -> mult -> LN -> gelu ----------------
__device__ __forceinline__ float waveReduce(float v) {
    #pragma unroll
    for (int off = 32; off > 0; off >>= 1) v += __shfl_down(v, off, 64);
    return v;
}
__device__ __forceinline__ float gelu_exact(float x) {
    return 0.5f * x * (1.0f + erff(x * 0.70710678118654752f));
}

__global__ __launch_bounds__(256)
void fuse_ln(const u16* __restrict__ y_raw, const u16* __restrict__ gate_pre, u16* __restrict__ y3) {
    int row = blockIdx.x;
    int tid = threadIdx.x;
    int wave = tid >> 6, lane = tid & 63;
    size_t base = (size_t)row * Nsz + tid * 4;
    ushort4 yv = *(const ushort4*)(y_raw + base);
    ushort4 gv = *(const ushort4*)(gate_pre + base);
    float y[4] = { b2f(yv.x), b2f(yv.y), b2f(yv.z), b2f(yv.w) };
    float g[4] = { b2f(gv.x), b2f(gv.y), b2f(gv.z), b2f(gv.w) };

    float sy = 0.f, sy2 = 0.f, sg = 0.f, sg2 = 0.f;
    #pragma unroll
    for (int i = 0; i < 4; ++i) {
        sy += y[i]; sy2 += y[i] * y[i];
        sg += g[i]; sg2 += g[i] * g[i];
    }
    __shared__ float sh[16];
    sy = waveReduce(sy); sy2 = waveReduce(sy2);
    sg = waveReduce(sg); sg2 = waveReduce(sg2);
    if (lane == 0) { sh[wave] = sy; sh[wave + 4] = sy2; sh[wave + 8] = sg; sh[wave + 12] = sg2; }
    __syncthreads();
    sy  = sh[0] + sh[1] + sh[2] + sh[3];
    sy2 = sh[4] + sh[5] + sh[6] + sh[7];
    sg  = sh[8] + sh[9] + sh[10] + sh[11];
    sg2 = sh[12] + sh[13] + sh[14] + sh[15];
    const float inv = 1.0f / (float)Nsz;
    float muy = sy * inv, vary = sy2 * inv - muy * muy, ry = rsqrtf(vary + 1e-5f);
    float mug = sg * inv, varg = sg2 * inv - mug * mug, rg = rsqrtf(varg + 1e-5f);

    float y2[4]; float s2 = 0.f, s22 = 0.f;
    #pragma unroll
    for (int i = 0; i < 4; ++i) {
        float ly = (y[i] - muy) * ry;
        float lg = (g[i] - mug) * rg;
        float t = ly * gelu_exact(lg);
        y2[i] = t; s2 += t; s22 += t * t;
    }
    s2 = waveReduce(s2); s22 = waveReduce(s22);
    __syncthreads();
    if (lane == 0) { sh[wave] = s2; sh[wave + 4] = s22; }
    __syncthreads();
    s2  = sh[0] + sh[1] + sh[2] + sh[3];
    s22 = sh[4] + sh[5] + sh[6] + sh[7];
    float mu2 = s2 * inv, var2 = s22 * inv - mu2 * mu2, r2 = rsqrtf(var2 + 1e-5f);
    ushort4 ov;
    ov.x = f2b(gelu_exact((y2[0] - mu2) * r2));
    ov.y = f2b(gelu_exact((y2[1] - mu2) * r2));
    ov.z = f2b(gelu_exact((y2[2] - mu2) * r2));
    ov.w = f2b(gelu_exact((y2[3] - mu2) * r2));
    *(ushort4*)(y3 + base) = ov;
}

// ---------------- host launch ----------------
extern "C" void kernel_launch(void* const* d_in, const int* in_sizes, int n_in,
                              void* d_out, int out_size, void* d_ws, size_t ws_size,
                              hipStream_t stream) {
    const float* x         = (const float*)d_in[0];
    const float* hid_re    = (const float*)d_in[1];
    const float* hid_im    = (const float*)d_in[2];
    const float* nu_log    = (const float*)d_in[3];
    const float* theta_log = (const float*)d_in[4];
    const float* B_re      = (const float*)d_in[5];
    const float* B_im      = (const float*)d_in[6];
    const float* C_re      = (const float*)d_in[7];
    const float* C_im      = (const float*)d_in[8];
    const float* D_skip    = (const float*)d_in[9];
    const float* W_gate    = (const float*)d_in[10];
    const float* W_con     = (const float*)d_in[11];
    float* out = (float*)d_out;

    char* ws = (char*)d_ws;
    const size_t MB = 1ull << 20;
    u16* wBre  = (u16*)(ws + 0 * MB);
    u16* wBim  = (u16*)(ws + 2 * MB);
    u16* wCre  = (u16*)(ws + 4 * MB);
    u16* wCimN = (u16*)(ws + 6 * MB);
    u16* wDsk  = (u16*)(ws + 8 * MB);
    u16* wWg   = (u16*)(ws + 10 * MB);
    u16* wWc   = (u16*)(ws + 12 * MB);
    float* lam_re = (float*)(ws + 14 * MB);
    float* lam_im = lam_re + 1024;
    float* gam    = lam_re + 2048;
    float* lamLre = lam_re + 3072;
    float* lamLim = lam_re + 4096;
    u16* xb    = (u16*)(ws + 16 * MB);
    u16* u_re  = (u16*)(ws + 48 * MB);
    u16* u_im  = (u16*)(ws + 80 * MB);
    u16* gate  = (u16*)(ws + 112 * MB);
    u16* hs_re = (u16*)(ws + 144 * MB);
    u16* hs_im = (u16*)(ws + 176 * MB);
    float* carry_re = (float*)(ws + 208 * MB);
    float* carry_im = (float*)(ws + 210 * MB);
    float* entry_re = (float*)(ws + 212 * MB);
    float* entry_im = (float*)(ws + 214 * MB);
    u16* y_raw = u_re;  // alias: u dead after scan_phase3
    u16* y3    = u_im;  // alias

    // merged converts (1 dispatch)
    CvtJobs J = {};
    const int WQ = (Nsz * Dsz) / 4;        // 262144 quads per weight
    const int WB = WQ / 256;               // 1024 blocks per weight
    J.src[0] = x;      J.dst[0] = xb;    J.n4[0] = (Msz * Dsz) / 4; J.scale[0] = 1.0f;
    J.src[1] = B_re;   J.dst[1] = wBre;  J.n4[1] = WQ; J.scale[1] = 1.0f;
    J.src[2] = B_im;   J.dst[2] = wBim;  J.n4[2] = WQ; J.scale[2] = 1.0f;
    J.src[3] = C_re;   J.dst[3] = wCre;  J.n4[3] = WQ; J.scale[3] = 1.0f;
    J.src[4] = C_im;   J.dst[4] = wCimN; J.n4[4] = WQ; J.scale[4] = -1.0f;
    J.src[5] = D_skip; J.dst[5] = wDsk;  J.n4[5] = WQ; J.scale[5] = 1.0f;
    J.src[6] = W_gate; J.dst[6] = wWg;   J.n4[6] = WQ; J.scale[6] = 1.0f;
    J.src[7] = W_con;  J.dst[7] = wWc;   J.n4[7] = WQ; J.scale[7] = 1.0f;
    J.blk_start[0] = 0;
    J.blk_start[1] = 16384;
    for (int t = 2; t <= 8; ++t) J.blk_start[t] = J.blk_start[t - 1] + WB;
    cvt_multi<<<J.blk_start[8], 256, 0, stream>>>(J);
    lam_setup<<<4, 256, 0, stream>>>(nu_log, theta_log, lam_re, lam_im, gam, lamLre, lamLim);

    // GEMM batch 1: u_re, u_im (gamma-scaled), gate_pre
    GemmBatch b1 = {};
    b1.j[0] = { xb, wBre, nullptr, nullptr, nullptr, nullptr, 1, nullptr, u_re, gam };
    b1.j[1] = { xb, wBim, nullptr, nullptr, nullptr, nullptr, 1, nullptr, u_im, gam };
    b1.j[2] = { xb, wWg,  nullptr, nullptr, nullptr, nullptr, 1, nullptr, gate, nullptr };
    gemm_bt<<<dim3(Msz / BM, Nsz / BN, 3), 256, 0, stream>>>(b1);

    // scan
    scan_phase1<<<dim3(CHUNKS, Bsz), 256, 0, stream>>>(u_re, u_im, lam_re, lam_im, carry_re, carry_im);
    scan_phase2<<<dim3(Nsz / 256, Bsz), 256, 0, stream>>>(carry_re, carry_im, lamLre, lamLim,
                                                          hid_re, hid_im, entry_re, entry_im, out);
    scan_phase3<<<dim3(CHUNKS, Bsz), 256, 0, stream>>>(u_re, u_im, lam_re, lam_im,
                                                       entry_re, entry_im, hs_re, hs_im);

    // GEMM batch 2: y_raw = hs_re*C_re^T + hs_im*(-C_im)^T + x*D_skip^T
    GemmBatch b2 = {};
    b2.j[0] = { hs_re, wCre, hs_im, wCimN, xb, wDsk, 3, nullptr, y_raw, nullptr };
    gemm_bt<<<dim3(Msz / BM, Nsz / BN, 1), 256, 0, stream>>>(b2);

    // fused LN / gate / gelu
    fuse_ln<<<Msz, 256, 0, stream>>>(y_raw, gate, y3);

    // GEMM 3: out = y3 * W_con^T  (fp32 out)
    GemmBatch b3 = {};
    b3.j[0] = { y3, wWc, nullptr, nullptr, nullptr, nullptr, 1, out, nullptr, nullptr };
    gemm_bt<<<dim3(Msz / BM, Dsz / BN, 1), 256, 0, stream>>>(b3);

    (void)in_sizes; (void)n_in; (void)out_size; (void)ws_size;
}